// Round 1
// 1234.428 us; speedup vs baseline: 1.0054x; 1.0054x over previous
//
#include <hip/hip_runtime.h>
#include <hip/hip_bf16.h>
#include <cstdint>
#include <cstddef>

#define NE 8          // experts
#define TK 2          // top-k
#define DM 1024       // hidden
#define IM 4096       // intermediate
#define NT 8192       // tokens (4*2048)
#define NS (NT*TK)    // total slots = 16384 (exact)
#define SCAP (NS+256) // padded rows for 256-row gemm1 tile overhang

typedef __bf16 bf16_t;
typedef __bf16 bf16x8 __attribute__((ext_vector_type(8)));
typedef __bf16 bf16x4 __attribute__((ext_vector_type(4)));
typedef float f32x4 __attribute__((ext_vector_type(4)));

// async global->LDS, 16B per lane. LDS side must be wave-uniform base + lane*16.
__device__ __forceinline__ void async_cp16(const bf16_t* g, bf16_t* l) {
  __builtin_amdgcn_global_load_lds(
      (__attribute__((address_space(1))) void*)(const_cast<bf16_t*>(g)),
      (__attribute__((address_space(3))) void*)(l), 16, 0, 0);
}

// ---------------- transpose + fp32->bf16 convert: src [z][R][C] f32 -> dst [z][C][R] bf16
__global__ void transpose_cvt(const float* __restrict__ src, bf16_t* __restrict__ dst,
                              int R, int C) {
  __shared__ float t[32][33];
  int bx = blockIdx.x * 32, by = blockIdx.y * 32;
  size_t zb = (size_t)blockIdx.z * R * C;
  int tx = threadIdx.x, ty = threadIdx.y;   // 32 x 8
#pragma unroll
  for (int i = 0; i < 4; ++i)
    t[ty + i*8][tx] = src[zb + (size_t)(by + ty + i*8) * C + bx + tx];
  __syncthreads();
#pragma unroll
  for (int i = 0; i < 4; ++i)
    dst[zb + (size_t)(bx + ty + i*8) * R + by + tx] = (bf16_t)t[tx][ty + i*8];
}

// ---------------- pack wg+wu -> Wgu[e][2*IM][DM] bf16, interleaved 64-col groups:
// packed row p: block=p>>7, sel=(p>>6)&1, r=p&63 -> source col block*64+r of (sel?wu:wg)
__global__ void pack_gu(const float* __restrict__ wg, const float* __restrict__ wu,
                        bf16_t* __restrict__ Wgu) {
  __shared__ float t[32][33];
  int sel = blockIdx.z & 1, e = blockIdx.z >> 1;
  const float* src = sel ? wu : wg;
  size_t zb = (size_t)e * DM * IM;
  int bx = blockIdx.x * 32, by = blockIdx.y * 32;   // bx: i-cols, by: d-rows
  int tx = threadIdx.x, ty = threadIdx.y;           // 32 x 8
#pragma unroll
  for (int i = 0; i < 4; ++i)
    t[ty + i*8][tx] = src[zb + (size_t)(by + ty + i*8) * IM + bx + tx];
  __syncthreads();
#pragma unroll
  for (int i = 0; i < 4; ++i) {
    int icol = bx + ty + i*8;
    int p = ((icol >> 6) << 7) + (sel << 6) + (icol & 63);
    Wgu[((size_t)e * (2*IM) + p) * DM + by + tx] = (bf16_t)t[tx][ty + i*8];
  }
}

// ---------------- router: logits, softmax, top-2, renorm; per-expert counts + prob sums
__global__ void router_kernel(const float* __restrict__ x, const float* __restrict__ wgate,
                              int* __restrict__ counts, float* __restrict__ prob_sum,
                              int* __restrict__ topk_idx, float* __restrict__ topk_w) {
  __shared__ float s_psum[NE];
  __shared__ int s_cnt[NE];
  int tid = threadIdx.x;
  if (tid < NE) { s_psum[tid] = 0.f; s_cnt[tid] = 0; }
  __syncthreads();
  int lane = tid & 63, wv = tid >> 6;
  for (int t = 0; t < 8; ++t) {             // 4 waves x 8 tokens = 32 tokens/block
    int n = blockIdx.x * 32 + wv * 8 + t;
    float acc[NE];
#pragma unroll
    for (int e = 0; e < NE; ++e) acc[e] = 0.f;
#pragma unroll
    for (int j = 0; j < 16; ++j) {
      int d = j * 64 + lane;
      float xv = x[(size_t)n * DM + d];
#pragma unroll
      for (int e = 0; e < NE; ++e) acc[e] += xv * wgate[e * DM + d];
    }
#pragma unroll
    for (int e = 0; e < NE; ++e) {
#pragma unroll
      for (int off = 32; off > 0; off >>= 1) acc[e] += __shfl_xor(acc[e], off);
    }
    if (lane == 0) {
      float mx = acc[0];
#pragma unroll
      for (int e = 1; e < NE; ++e) mx = fmaxf(mx, acc[e]);
      float p[NE], s = 0.f;
#pragma unroll
      for (int e = 0; e < NE; ++e) { p[e] = __expf(acc[e] - mx); s += p[e]; }
      float inv = 1.f / s;
#pragma unroll
      for (int e = 0; e < NE; ++e) p[e] *= inv;
      int i0 = 0;
      for (int e = 1; e < NE; ++e) if (p[e] > p[i0]) i0 = e;     // ties -> lower idx (matches top_k)
      int i1 = (i0 == 0) ? 1 : 0;
      for (int e = 0; e < NE; ++e) if (e != i0 && p[e] > p[i1]) i1 = e;
      float rs = 1.f / (p[i0] + p[i1]);
      topk_idx[n * 2 + 0] = i0; topk_idx[n * 2 + 1] = i1;
      topk_w[n * 2 + 0] = p[i0] * rs; topk_w[n * 2 + 1] = p[i1] * rs;
      atomicAdd(&s_cnt[i0], 1); atomicAdd(&s_cnt[i1], 1);
#pragma unroll
      for (int e = 0; e < NE; ++e) atomicAdd(&s_psum[e], p[e]);
    }
  }
  __syncthreads();
  if (tid < NE) { atomicAdd(&counts[tid], s_cnt[tid]); atomicAdd(&prob_sum[tid], s_psum[tid]); }
}

// ---------------- exclusive scan of counts (8 elems), cursors, aux loss
__global__ void scan_aux(const int* __restrict__ counts, const float* __restrict__ prob_sum,
                         int* __restrict__ offsets, int* __restrict__ cursors,
                         float* __restrict__ aux_out) {
  if (threadIdx.x == 0) {
    int off = 0;
    float aux = 0.f;
    for (int e = 0; e < NE; ++e) {
      offsets[e] = off; cursors[e] = off;
      float f = (float)counts[e] * (1.f / (float)NS);
      float p = prob_sum[e] * (1.f / (float)NT);
      aux += f * p;
      off += counts[e];
    }
    offsets[NE] = off;
    *aux_out = 0.02f * 8.f * aux;
  }
}

// ---------------- gather tokens into per-expert compact bf16 rows (vectorized f32x4->bf16x4)
__global__ void gather_kernel(const float* __restrict__ x, const int* __restrict__ topk_idx,
                              const float* __restrict__ topk_w, int* __restrict__ cursors,
                              int* __restrict__ slot_token, float* __restrict__ slot_w,
                              int* __restrict__ pair_slot, bf16_t* __restrict__ Xg) {
  int lane = threadIdx.x & 63, wv = threadIdx.x >> 6;
  int pair = blockIdx.x * 4 + wv;           // (token, k)
  int n = pair >> 1, k = pair & 1;
  int e = topk_idx[n * 2 + k];
  int slot = 0;
  if (lane == 0) slot = atomicAdd(&cursors[e], 1);
  slot = __shfl(slot, 0);
  if (lane == 0) {
    slot_token[slot] = n; slot_w[slot] = topk_w[n * 2 + k];
    pair_slot[pair] = slot;
  }
#pragma unroll
  for (int j = 0; j < 4; ++j) {
    int d4 = j * 256 + lane * 4;
    float4 v = *(const float4*)(x + (size_t)n * DM + d4);
    bf16x4 o;
    o[0] = (bf16_t)v.x; o[1] = (bf16_t)v.y; o[2] = (bf16_t)v.z; o[3] = (bf16_t)v.w;
    *(bf16x4*)(Xg + (size_t)slot * DM + d4) = o;
  }
}

// ============ GEMM1: 256x256-tile, 8-phase (T2+T3+T4+T5), packed Wgu B-operand ============
// H = silu(Xg@Wg') * (Xg@Wu') per expert. B = Wgu packed rows (64 g-cols | 64 u-cols alternating),
// so a 256-row B-tile = 128 H-cols, and per-wave N-frag pairs (j=0,1)/(j=2,3) are (g,u) of the
// SAME H-col in the SAME lane -> in-register SwiGLU epilogue.
// Wave grid 2Mx4N, per-wave 128x64. Interleaved frag->row map: m-frag i -> tile row i*32+wm*16,
// so A-half0 (rows 0-127) = frags 0-3 of BOTH wm classes (enables half-granular phase schedule).
// LDS 2 bufs x 4 regions (A0,A1,B0,B1) x 128x64 bf16 = 128 KiB. XOR-swizzle chunk c8^(r&7).
// Phase schedule per K-step t (BK=64, NTK=16):
//   P0: read A0-frags(8)+B0-frags(4); stage (t+1,A1); bar; lgkm0; 16 MFMA Q0(m0-3 x j0-1); bar
//   P1: read B1-frags(4);             stage (t+2,A0); bar; lgkm0; 16 MFMA Q1(m0-3 x j2-3); bar
//   P2: read A1-frags(8, reuse af);   stage (t+2,B0); bar; lgkm0; 16 MFMA Q2(m4-7 x j0-1); bar
//   P3:                               stage (t+2,B1); vmcnt(6); bar; 16 MFMA Q3;           bar
// Stage stream = region death order (A0,B0 die P0; B1 dies P1; A1 dies P2) -> every overwrite
// lands after its readers' lgkm0+barrier. vmcnt(6)=3 half-tiles in flight; drain 0 at t=NTK-2.
#define MFMA16 __builtin_amdgcn_mfma_f32_16x16x32_bf16

__global__ __launch_bounds__(512, 2) void gemm1_kernel(
    const bf16_t* __restrict__ Xg, const bf16_t* __restrict__ Wgu,
    bf16_t* __restrict__ H, const int* __restrict__ offsets) {
  int e = blockIdx.z, mt = blockIdx.y, nt = blockIdx.x;
  int row0 = offsets[e], ne = offsets[e + 1] - row0;
  if (mt * 256 >= ne) return;
  int m0 = row0 + mt * 256;

  __shared__ bf16_t lds[2][4][128 * 64];   // [buf][region: 0=A0,1=A1,2=B0,3=B1]

  int tid = threadIdx.x, lane = tid & 63, wv = tid >> 6;
  int fm = lane & 15, fq = lane >> 4;
  int wm = wv >> 2, wn = wv & 3;

  const bf16_t* Ab = Xg + (size_t)m0 * DM;
  const bf16_t* Bb = Wgu + ((size_t)e * (2 * IM) + nt * 256) * DM;

  // staging invariants: thread covers chunks tid (row sr) and 512+tid (row sr+64, same swizzle)
  int sr = tid >> 3;
  int sgc = ((tid & 7) ^ (sr & 7)) << 3;   // inverse-swizzled source col (elems)
  int sldo = tid * 8;                      // linear LDS elem offset (is=0); +4096 for is=1

#define STAGE1(LDST, GBASE, COL) do {                                      \
    const bf16_t* _g = (GBASE);                                            \
    async_cp16(_g + (size_t)sr * DM + (COL) + sgc, (LDST) + sldo);         \
    async_cp16(_g + (size_t)(sr + 64) * DM + (COL) + sgc, (LDST) + sldo + 4096); \
  } while (0)

  // ds_read offsets (elems within a 128x64 region); same for both halves of A (and of B)
  int offA[4][2], offB[2][2];
#pragma unroll
  for (int m = 0; m < 4; ++m) {
    int r = m * 32 + wm * 16 + fm;
#pragma unroll
    for (int ks = 0; ks < 2; ++ks)
      offA[m][ks] = r * 64 + (((ks * 4 + fq) ^ (r & 7)) << 3);
  }
#pragma unroll
  for (int jh = 0; jh < 2; ++jh) {
    int r = jh * 64 + wn * 16 + fm;
#pragma unroll
    for (int ks = 0; ks < 2; ++ks)
      offB[jh][ks] = r * 64 + (((ks * 4 + fq) ^ (r & 7)) << 3);
  }

  f32x4 acc[8][4];
#pragma unroll
  for (int i = 0; i < 8; ++i)
#pragma unroll
    for (int j = 0; j < 4; ++j) acc[i][j] = (f32x4){0.f, 0.f, 0.f, 0.f};

  // prologue: stream halves h0..h6 = (0,A0)(0,B0)(0,B1)(0,A1)(1,A0)(1,B0)(1,B1)
  STAGE1(lds[0][0], Ab, 0);
  STAGE1(lds[0][2], Bb, 0);
  STAGE1(lds[0][3], Bb + (size_t)128 * DM, 0);
  STAGE1(lds[0][1], Ab + (size_t)128 * DM, 0);
  STAGE1(lds[1][0], Ab, 64);
  STAGE1(lds[1][2], Bb, 64);
  STAGE1(lds[1][3], Bb + (size_t)128 * DM, 64);
  asm volatile("s_waitcnt vmcnt(6)");      // h0..h3 (= all of K-step 0) landed
  __builtin_amdgcn_s_barrier();

  bf16x8 af[4][2], b0f[2][2], b1f[2][2];
#pragma unroll 1
  for (int t = 0; t < 16; ++t) {
    const int buf = t & 1;
    const bf16_t* LA0 = lds[buf][0];
    const bf16_t* LA1 = lds[buf][1];
    const bf16_t* LB0 = lds[buf][2];
    const bf16_t* LB1 = lds[buf][3];
    // ---- P0
#pragma unroll
    for (int m = 0; m < 4; ++m) {
      af[m][0] = *(const bf16x8*)(LA0 + offA[m][0]);
      af[m][1] = *(const bf16x8*)(LA0 + offA[m][1]);
    }
#pragma unroll
    for (int j = 0; j < 2; ++j) {
      b0f[j][0] = *(const bf16x8*)(LB0 + offB[j][0]);
      b0f[j][1] = *(const bf16x8*)(LB0 + offB[j][1]);
    }
    if (t + 1 < 16) STAGE1(lds[buf ^ 1][1], Ab + (size_t)128 * DM, (t + 1) * 64);
    __builtin_amdgcn_s_barrier();
    asm volatile("s_waitcnt lgkmcnt(0)");
    __builtin_amdgcn_sched_barrier(0);
    __builtin_amdgcn_s_setprio(1);
#pragma unroll
    for (int m = 0; m < 4; ++m)
#pragma unroll
      for (int j = 0; j < 2; ++j) {
        acc[m][j] = MFMA16(af[m][0], b0f[j][0], acc[m][j], 0, 0, 0);
        acc[m][j] = MFMA16(af[m][1], b0f[j][1], acc[m][j], 0, 0, 0);
      }
    __builtin_amdgcn_s_setprio(0);
    __builtin_amdgcn_s_barrier();
    // ---- P1
#pragma unroll
    for (int j = 0; j < 2; ++j) {
      b1f[j][0] = *(const bf16x8*)(LB1 + offB[j][0]);
      b1f[j][1] = *(const bf16x8*)(LB1 + offB[j][1]);
    }
    if (t + 2 < 16) STAGE1(lds[buf][0], Ab, (t + 2) * 64);
    __builtin_amdgcn_s_barrier();
    asm volatile("s_waitcnt lgkmcnt(0)");
    __builtin_amdgcn_sched_barrier(0);
    __builtin_amdgcn_s_setprio(1);
#pragma unroll
    for (int m = 0; m < 4; ++m)
#pragma unroll
      for (int j = 0; j < 2; ++j) {
        acc[m][2 + j] = MFMA16(af[m][0], b1f[j][0], acc[m][2 + j], 0, 0, 0);
        acc[m][2 + j] = MFMA16(af[m][1], b1f[j][1], acc[m][2 + j], 0, 0, 0);
      }
    __builtin_amdgcn_s_setprio(0);
    __builtin_amdgcn_s_barrier();
    // ---- P2
#pragma unroll
    for (int m = 0; m < 4; ++m) {
      af[m][0] = *(const bf16x8*)(LA1 + offA[m][0]);
      af[m][1] = *(const bf16x8*)(LA1 + offA[m][1]);
    }
    if (t + 2 < 16) STAGE1(lds[buf][2], Bb, (t + 2) * 64);
    __builtin_amdgcn_s_barrier();
    asm volatile("s_waitcnt lgkmcnt(0)");
    __builtin_amdgcn_sched_barrier(0);
    __builtin_amdgcn_s_setprio(1);
#pragma unroll
    for (int m = 0; m < 4; ++m)
#pragma unroll
      for (int j = 0; j < 2; ++j) {
        acc[4 + m][j] = MFMA16(af[m][0], b0f[j][0], acc[4 + m][j], 0, 0, 0);
        acc[4 + m][j] = MFMA16(af[m][1], b0f[j][1], acc[4 + m][j], 0, 0, 0);
      }
    __builtin_amdgcn_s_setprio(0);
    __builtin_amdgcn_s_barrier();
    // ---- P3
    if (t + 2 < 16) STAGE1(lds[buf][3], Bb + (size_t)128 * DM, (t + 2) * 64);
    if (t < 14) { asm volatile("s_waitcnt vmcnt(6)"); }
    else if (t == 14) { asm volatile("s_waitcnt vmcnt(0)"); }
    __builtin_amdgcn_s_barrier();
    __builtin_amdgcn_s_setprio(1);
#pragma unroll
    for (int m = 0; m < 4; ++m)
#pragma unroll
      for (int j = 0; j < 2; ++j) {
        acc[4 + m][2 + j] = MFMA16(af[m][0], b1f[j][0], acc[4 + m][2 + j], 0, 0, 0);
        acc[4 + m][2 + j] = MFMA16(af[m][1], b1f[j][1], acc[4 + m][2 + j], 0, 0, 0);
      }
    __builtin_amdgcn_s_setprio(0);
    __builtin_amdgcn_s_barrier();
  }
#undef STAGE1

  // epilogue: acc[i][0,1]=(g,u) H-col wn*16+fm; acc[i][2,3]=(g,u) H-col 64+wn*16+fm
#pragma unroll
  for (int i = 0; i < 8; ++i) {
    int lr = i * 32 + wm * 16 + fq * 4;
#pragma unroll
    for (int rr = 0; rr < 4; ++rr) {
      if (mt * 256 + lr + rr < ne) {
        bf16_t* hp = H + (size_t)(m0 + lr + rr) * IM + nt * 128 + wn * 16 + fm;
        float g0 = acc[i][0][rr], u0 = acc[i][1][rr];
        hp[0] = (bf16_t)(g0 * __builtin_amdgcn_rcpf(1.f + __expf(-g0)) * u0);
        float g1 = acc[i][2][rr], u1 = acc[i][3][rr];
        hp[64] = (bf16_t)(g1 * __builtin_amdgcn_rcpf(1.f + __expf(-g1)) * u1);
      }
    }
  }
}

// ---------------- GEMM2: Y[slot] = H[slot] @ WdT' (unweighted, bf16 out; combine applies weights)
__global__ __launch_bounds__(256, 2) void gemm2_kernel(
    const bf16_t* __restrict__ H, const bf16_t* __restrict__ Wdt,
    const int* __restrict__ offsets, bf16_t* __restrict__ Y) {
  int e = blockIdx.z, mt = blockIdx.y, nt = blockIdx.x;
  int row0 = offsets[e], ne = offsets[e + 1] - row0;
  if (mt * 128 >= ne) return;
  int m0 = row0 + mt * 128;
  int n0 = nt * 128;

  __shared__ bf16_t sA[128 * 64];
  __shared__ bf16_t sB[128 * 64];

  int tid = threadIdx.x, lane = tid & 63, wv = tid >> 6;
  int fm = lane & 15, fq = lane >> 4;
  int wm = (wv & 1) * 64, wn = (wv >> 1) * 64;

  f32x4 acc[4][4];
#pragma unroll
  for (int i = 0; i < 4; ++i)
#pragma unroll
    for (int j = 0; j < 4; ++j) acc[i][j] = (f32x4){0.f, 0.f, 0.f, 0.f};

  const bf16_t* Ab = H + (size_t)m0 * IM;
  const bf16_t* Bb = Wdt + ((size_t)e * DM + n0) * IM;

  for (int k0 = 0; k0 < IM; k0 += 64) {
    __syncthreads();
#pragma unroll
    for (int it = 0; it < 4; ++it) {
      int c = it * 256 + tid;
      int r = c >> 3, c8 = c & 7;
      int gc8 = c8 ^ (r & 7);
      size_t go = (size_t)r * IM + k0 + gc8 * 8;
      async_cp16(Ab + go, sA + c * 8);
      async_cp16(Bb + go, sB + c * 8);
    }
    __syncthreads();
#pragma unroll
    for (int s = 0; s < 2; ++s) {
      bf16x8 af[4], bf[4];
      int q = s * 4 + fq;
#pragma unroll
      for (int i = 0; i < 4; ++i) {
        int ra = wm + i * 16 + fm;
        int rb = wn + i * 16 + fm;
        af[i] = *(const bf16x8*)(sA + ra * 64 + (q ^ (ra & 7)) * 8);
        bf[i] = *(const bf16x8*)(sB + rb * 64 + (q ^ (rb & 7)) * 8);
      }
#pragma unroll
      for (int i = 0; i < 4; ++i)
#pragma unroll
        for (int j = 0; j < 4; ++j)
          acc[i][j] = __builtin_amdgcn_mfma_f32_16x16x32_bf16(af[i], bf[j], acc[i][j], 0, 0, 0);
    }
  }
#pragma unroll
  for (int i = 0; i < 4; ++i) {
#pragma unroll
    for (int r = 0; r < 4; ++r) {
      int lm = wm + i * 16 + fq * 4 + r;
      if (mt * 128 + lm < ne) {
        bf16_t* yrow = Y + (size_t)(m0 + lm) * DM + n0 + wn;
#pragma unroll
        for (int j = 0; j < 4; ++j)
          yrow[j * 16 + fm] = (bf16_t)acc[i][j][r];
      }
    }
  }
}

// ---------------- combine: out[n] = w0 * Y[slot(n,0)] + w1 * Y[slot(n,1)]
__global__ void combine_kernel(const bf16_t* __restrict__ Y, const int* __restrict__ pair_slot,
                               const float* __restrict__ topk_w, float* __restrict__ out) {
  int n = blockIdx.x;
  int t = threadIdx.x;
  int s0 = pair_slot[n * 2 + 0], s1 = pair_slot[n * 2 + 1];
  float w0 = topk_w[n * 2 + 0], w1 = topk_w[n * 2 + 1];
  bf16x4 y0 = *(const bf16x4*)(Y + (size_t)s0 * DM + t * 4);
  bf16x4 y1 = *(const bf16x4*)(Y + (size_t)s1 * DM + t * 4);
  float4 o;
  o.x = w0 * (float)y0[0] + w1 * (float)y1[0];
  o.y = w0 * (float)y0[1] + w1 * (float)y1[1];
  o.z = w0 * (float)y0[2] + w1 * (float)y1[2];
  o.w = w0 * (float)y0[3] + w1 * (float)y1[3];
  *(float4*)(out + (size_t)n * DM + t * 4) = o;
}

// ---------------- workspace layout (bytes)
static constexpr size_t OFF_TOPKI = 256;                               // [NT][2] i32
static constexpr size_t OFF_TOPKW = OFF_TOPKI + (size_t)NT * 2 * 4;    // [NT][2] f32
static constexpr size_t OFF_STOK  = OFF_TOPKW + (size_t)NT * 2 * 4;    // [NS] i32
static constexpr size_t OFF_SW    = OFF_STOK + (size_t)NS * 4;         // [NS] f32
static constexpr size_t OFF_PSLOT = OFF_SW + (size_t)NS * 4;           // [NS] i32
static constexpr size_t OFF_XG    = OFF_PSLOT + (size_t)NS * 4;        // [SCAP][DM] bf16 (Y aliases)
static constexpr size_t OFF_H     = OFF_XG + (size_t)SCAP * DM * 2;    // [SCAP][IM] bf16
static constexpr size_t OFF_WGU   = OFF_H + (size_t)SCAP * IM * 2;     // [NE][2*IM][DM] bf16
static constexpr size_t OFF_WDT   = OFF_WGU + (size_t)NE * 2 * IM * DM * 2; // [NE][DM][IM] bf16

extern "C" void kernel_launch(void* const* d_in, const int* in_sizes, int n_in,
                              void* d_out, int out_size, void* d_ws, size_t ws_size,
                              hipStream_t stream) {
  const float* x      = (const float*)d_in[0];
  const float* w_gate = (const float*)d_in[1];
  const float* wg     = (const float*)d_in[2];
  const float* wu     = (const float*)d_in[3];
  const float* wd     = (const float*)d_in[4];
  float* out = (float*)d_out;

  char* ws = (char*)d_ws;
  int*   counts   = (int*)(ws + 0);
  int*   cursors  = (int*)(ws + 32);
  int*   offsets  = (int*)(ws + 64);
  float* prob_sum = (float*)(ws + 128);
  int*   topk_idx = (int*)(ws + OFF_TOPKI);
  float* topk_w   = (float*)(ws + OFF_TOPKW);
  int*   slot_tok = (int*)(ws + OFF_STOK);
  float* slot_w   = (float*)(ws + OFF_SW);
  int*   pair_slot= (int*)(ws + OFF_PSLOT);
  bf16_t* Xg  = (bf16_t*)(ws + OFF_XG);
  bf16_t* Yb  = Xg;                          // Y aliases Xg (dead after gemm1; same size)
  bf16_t* Hb  = (bf16_t*)(ws + OFF_H);
  bf16_t* Wgu = (bf16_t*)(ws + OFF_WGU);
  bf16_t* Wdt = (bf16_t*)(ws + OFF_WDT);

  hipMemsetAsync(ws, 0, 256, stream);

  // weight convert: wg+wu -> packed Wgu [2*IM][DM]; wd -> Wdt [DM][IM]
  pack_gu<<<dim3(IM / 32, DM / 32, NE * 2), dim3(32, 8), 0, stream>>>(wg, wu, Wgu);
  transpose_cvt<<<dim3(DM / 32, IM / 32, NE), dim3(32, 8), 0, stream>>>(wd, Wdt, IM, DM);

  router_kernel<<<NT / 32, 256, 0, stream>>>(x, w_gate, counts, prob_sum, topk_idx, topk_w);
  scan_aux<<<1, 64, 0, stream>>>(counts, prob_sum, offsets, cursors, out + (out_size - 1));
  gather_kernel<<<NS / 4, 256, 0, stream>>>(x, topk_idx, topk_w, cursors, slot_tok, slot_w,
                                            pair_slot, Xg);

  // gemm1: 256-row M tiles (64 = worst case), 128 H-cols per block; inactive tiles early-exit
  gemm1_kernel<<<dim3(IM / 128, 64, NE), 512, 0, stream>>>(Xg, Wgu, Hb, offsets);
  gemm2_kernel<<<dim3(DM / 128, 64, NE), 256, 0, stream>>>(Hb, Wdt, offsets, Yb);
  combine_kernel<<<NT, 256, 0, stream>>>(Yb, pair_slot, topk_w, out);
}

// Round 3
// 1183.355 us; speedup vs baseline: 1.0488x; 1.0432x over previous
//
#include <hip/hip_runtime.h>
#include <hip/hip_bf16.h>
#include <cstdint>
#include <cstddef>

#define NE 8          // experts
#define TK 2          // top-k
#define DM 1024       // hidden
#define IM 4096       // intermediate
#define NT 8192       // tokens (4*2048)
#define NS (NT*TK)    // total slots = 16384 (exact)
#define SCAP (NS+256) // padded rows for 256-row tile overhang
#define MAXT 72       // max 256-row tiles: sum ceil(ne/256) <= 64 + 7 = 71

typedef __bf16 bf16_t;
typedef __bf16 bf16x8 __attribute__((ext_vector_type(8)));
typedef __bf16 bf16x4 __attribute__((ext_vector_type(4)));
typedef float f32x4 __attribute__((ext_vector_type(4)));

// async global->LDS, 16B per lane. LDS side must be wave-uniform base + lane*16.
__device__ __forceinline__ void async_cp16(const bf16_t* g, bf16_t* l) {
  __builtin_amdgcn_global_load_lds(
      (__attribute__((address_space(1))) void*)(const_cast<bf16_t*>(g)),
      (__attribute__((address_space(3))) void*)(l), 16, 0, 0);
}

// ---------------- transpose + fp32->bf16 convert: src [z][R][C] f32 -> dst [z][C][R] bf16
__global__ void transpose_cvt(const float* __restrict__ src, bf16_t* __restrict__ dst,
                              int R, int C) {
  __shared__ float t[32][33];
  int bx = blockIdx.x * 32, by = blockIdx.y * 32;
  size_t zb = (size_t)blockIdx.z * R * C;
  int tx = threadIdx.x, ty = threadIdx.y;   // 32 x 8
#pragma unroll
  for (int i = 0; i < 4; ++i)
    t[ty + i*8][tx] = src[zb + (size_t)(by + ty + i*8) * C + bx + tx];
  __syncthreads();
#pragma unroll
  for (int i = 0; i < 4; ++i)
    dst[zb + (size_t)(bx + ty + i*8) * R + by + tx] = (bf16_t)t[tx][ty + i*8];
}

// ---------------- pack wg+wu -> Wgu[e][2*IM][DM] bf16, interleaved 64-col groups:
// packed row p: block=p>>7, sel=(p>>6)&1, r=p&63 -> source col block*64+r of (sel?wu:wg)
__global__ void pack_gu(const float* __restrict__ wg, const float* __restrict__ wu,
                        bf16_t* __restrict__ Wgu) {
  __shared__ float t[32][33];
  int sel = blockIdx.z & 1, e = blockIdx.z >> 1;
  const float* src = sel ? wu : wg;
  size_t zb = (size_t)e * DM * IM;
  int bx = blockIdx.x * 32, by = blockIdx.y * 32;   // bx: i-cols, by: d-rows
  int tx = threadIdx.x, ty = threadIdx.y;           // 32 x 8
#pragma unroll
  for (int i = 0; i < 4; ++i)
    t[ty + i*8][tx] = src[zb + (size_t)(by + ty + i*8) * IM + bx + tx];
  __syncthreads();
#pragma unroll
  for (int i = 0; i < 4; ++i) {
    int icol = bx + ty + i*8;
    int p = ((icol >> 6) << 7) + (sel << 6) + (icol & 63);
    Wgu[((size_t)e * (2*IM) + p) * DM + by + tx] = (bf16_t)t[tx][ty + i*8];
  }
}

// ---------------- router: logits, softmax, top-2, renorm; per-expert counts + prob sums
__global__ void router_kernel(const float* __restrict__ x, const float* __restrict__ wgate,
                              int* __restrict__ counts, float* __restrict__ prob_sum,
                              int* __restrict__ topk_idx, float* __restrict__ topk_w) {
  __shared__ float s_psum[NE];
  __shared__ int s_cnt[NE];
  int tid = threadIdx.x;
  if (tid < NE) { s_psum[tid] = 0.f; s_cnt[tid] = 0; }
  __syncthreads();
  int lane = tid & 63, wv = tid >> 6;
  for (int t = 0; t < 8; ++t) {             // 4 waves x 8 tokens = 32 tokens/block
    int n = blockIdx.x * 32 + wv * 8 + t;
    float acc[NE];
#pragma unroll
    for (int e = 0; e < NE; ++e) acc[e] = 0.f;
#pragma unroll
    for (int j = 0; j < 16; ++j) {
      int d = j * 64 + lane;
      float xv = x[(size_t)n * DM + d];
#pragma unroll
      for (int e = 0; e < NE; ++e) acc[e] += xv * wgate[e * DM + d];
    }
#pragma unroll
    for (int e = 0; e < NE; ++e) {
#pragma unroll
      for (int off = 32; off > 0; off >>= 1) acc[e] += __shfl_xor(acc[e], off);
    }
    if (lane == 0) {
      float mx = acc[0];
#pragma unroll
      for (int e = 1; e < NE; ++e) mx = fmaxf(mx, acc[e]);
      float p[NE], s = 0.f;
#pragma unroll
      for (int e = 0; e < NE; ++e) { p[e] = __expf(acc[e] - mx); s += p[e]; }
      float inv = 1.f / s;
#pragma unroll
      for (int e = 0; e < NE; ++e) p[e] *= inv;
      int i0 = 0;
      for (int e = 1; e < NE; ++e) if (p[e] > p[i0]) i0 = e;     // ties -> lower idx (matches top_k)
      int i1 = (i0 == 0) ? 1 : 0;
      for (int e = 0; e < NE; ++e) if (e != i0 && p[e] > p[i1]) i1 = e;
      float rs = 1.f / (p[i0] + p[i1]);
      topk_idx[n * 2 + 0] = i0; topk_idx[n * 2 + 1] = i1;
      topk_w[n * 2 + 0] = p[i0] * rs; topk_w[n * 2 + 1] = p[i1] * rs;
      atomicAdd(&s_cnt[i0], 1); atomicAdd(&s_cnt[i1], 1);
#pragma unroll
      for (int e = 0; e < NE; ++e) atomicAdd(&s_psum[e], p[e]);
    }
  }
  __syncthreads();
  if (tid < NE) { atomicAdd(&counts[tid], s_cnt[tid]); atomicAdd(&prob_sum[tid], s_psum[tid]); }
}

// ---------------- scan counts, cursors, aux loss, and build the 256-row tile list
__global__ void scan_aux(const int* __restrict__ counts, const float* __restrict__ prob_sum,
                         int* __restrict__ offsets, int* __restrict__ cursors,
                         float* __restrict__ aux_out, int* __restrict__ tl_m0,
                         int* __restrict__ tl_e, int* __restrict__ tl_rows,
                         int* __restrict__ n_tiles) {
  if (threadIdx.x == 0) {
    int off = 0;
    float aux = 0.f;
    int t = 0;
    for (int e = 0; e < NE; ++e) {
      offsets[e] = off; cursors[e] = off;
      int c = counts[e];
      float f = (float)c * (1.f / (float)NS);
      float p = prob_sum[e] * (1.f / (float)NT);
      aux += f * p;
      for (int m = 0; m * 256 < c && t < MAXT; ++m, ++t) {
        tl_m0[t] = off + m * 256;
        tl_e[t] = e;
        tl_rows[t] = min(256, c - m * 256);
      }
      off += c;
    }
    offsets[NE] = off;
    *n_tiles = t;
    *aux_out = 0.02f * 8.f * aux;
  }
}

// ---------------- gather tokens into per-expert compact bf16 rows (vectorized f32x4->bf16x4)
__global__ void gather_kernel(const float* __restrict__ x, const int* __restrict__ topk_idx,
                              const float* __restrict__ topk_w, int* __restrict__ cursors,
                              int* __restrict__ slot_token, float* __restrict__ slot_w,
                              int* __restrict__ pair_slot, bf16_t* __restrict__ Xg) {
  int lane = threadIdx.x & 63, wv = threadIdx.x >> 6;
  int pair = blockIdx.x * 4 + wv;           // (token, k)
  int n = pair >> 1, k = pair & 1;
  int e = topk_idx[n * 2 + k];
  int slot = 0;
  if (lane == 0) slot = atomicAdd(&cursors[e], 1);
  slot = __shfl(slot, 0);
  if (lane == 0) {
    slot_token[slot] = n; slot_w[slot] = topk_w[n * 2 + k];
    pair_slot[pair] = slot;
  }
#pragma unroll
  for (int j = 0; j < 4; ++j) {
    int d4 = j * 256 + lane * 4;
    float4 v = *(const float4*)(x + (size_t)n * DM + d4);
    bf16x4 o;
    o[0] = (bf16_t)v.x; o[1] = (bf16_t)v.y; o[2] = (bf16_t)v.z; o[3] = (bf16_t)v.w;
    *(bf16x4*)(Xg + (size_t)slot * DM + d4) = o;
  }
}

// ============ unified 256-tile MoE GEMM, software-pipelined 4-phase schedule ============
// Per block: 256 A-rows (tile list) x 256 B-rows (nt). 8 waves 2Mx4N, per-wave 128x64.
// LDS: 2 bufs x 4 regions (A0,A1,B0,B1) x 128x64 bf16 = 128 KiB, XOR-swizzled chunks.
// Phase k: [stage][pre-reads][counted lgkm][barrier][MFMA][post-reads] -- one barrier/phase;
// frag-reads for phase k are issued during phase k-1's MFMA window so LDS latency hides.
// Read schedule: B1(t)@P0-pre(lgkm 4); A1(t)@P1-post (reuses af regs after P1 MFMA);
// B0(t+1)@P3 after publication barrier; A0(t+1)@P3-post. vmcnt(6) at P3 drains exactly
// the 4 regions of step t+1 (verified by stage-stream simulation); drained to 0 at NTK-2.
// Stage death-order ledger: each stage lands >=1 barrier after its region's readers drained.
#define MFMA16 __builtin_amdgcn_mfma_f32_16x16x32_bf16
#define SBAR  __builtin_amdgcn_s_barrier
#define SCHED __builtin_amdgcn_sched_barrier
#define PRIO  __builtin_amdgcn_s_setprio

template<int NTK, int KSTR, int BROWS, bool SWIGLU>
__global__ __launch_bounds__(512, 2) void moe_gemm(
    const bf16_t* __restrict__ A, const bf16_t* __restrict__ Bw,
    bf16_t* __restrict__ O,
    const int* __restrict__ tl_m0, const int* __restrict__ tl_e,
    const int* __restrict__ tl_rows, const int* __restrict__ n_tiles) {
  int ty = blockIdx.y;
  if (ty >= *n_tiles) return;
  int m0 = tl_m0[ty];
  int e  = tl_e[ty];
  int rows = tl_rows[ty];
  int nt = blockIdx.x;

  __shared__ bf16_t lds[2][4][128 * 64];   // [buf][region: 0=A0,1=A1,2=B0,3=B1]

  int tid = threadIdx.x, lane = tid & 63, wv = tid >> 6;
  int fm = lane & 15, fq = lane >> 4;
  int wm = wv >> 2, wn = wv & 3;

  const bf16_t* Ab = A + (size_t)m0 * KSTR;
  const bf16_t* Bb = Bw + ((size_t)e * BROWS + (size_t)nt * 256) * KSTR;

  // staging: thread covers chunk tid (row sr) and row sr+64 (same swizzle phase)
  int sr = tid >> 3;
  int sgc = ((tid & 7) ^ (sr & 7)) << 3;   // inverse-swizzled source col (elems)
  int sldo = tid * 8;                      // linear LDS elem offset; +4096 for 2nd half

#define STG(LDST, GBASE, COL) do {                                         \
    const bf16_t* _g = (GBASE);                                            \
    async_cp16(_g + (size_t)sr * KSTR + (COL) + sgc, (LDST) + sldo);       \
    async_cp16(_g + (size_t)(sr + 64) * KSTR + (COL) + sgc, (LDST) + sldo + 4096); \
  } while (0)

  // ds_read elem offsets within a 128x64 region (XOR swizzle re-applied)
  int offA[4][2], offB[2][2];
#pragma unroll
  for (int m = 0; m < 4; ++m) {
    int r = m * 32 + wm * 16 + fm;
#pragma unroll
    for (int ks = 0; ks < 2; ++ks)
      offA[m][ks] = r * 64 + (((ks * 4 + fq) ^ (r & 7)) << 3);
  }
#pragma unroll
  for (int jh = 0; jh < 2; ++jh) {
    int r = jh * 64 + wn * 16 + fm;
#pragma unroll
    for (int ks = 0; ks < 2; ++ks)
      offB[jh][ks] = r * 64 + (((ks * 4 + fq) ^ (r & 7)) << 3);
  }

  f32x4 acc[8][4];
#pragma unroll
  for (int i = 0; i < 8; ++i)
#pragma unroll
    for (int j = 0; j < 4; ++j) acc[i][j] = (f32x4){0.f, 0.f, 0.f, 0.f};

  // prologue: stage halves (0,A0)(0,B0)(0,B1)(0,A1)(1,A0)(1,B0)(1,B1)
  STG(lds[0][0], Ab, 0);
  STG(lds[0][2], Bb, 0);
  STG(lds[0][3], Bb + (size_t)128 * KSTR, 0);
  STG(lds[0][1], Ab + (size_t)128 * KSTR, 0);
  STG(lds[1][0], Ab, 64);
  STG(lds[1][2], Bb, 64);
  STG(lds[1][3], Bb + (size_t)128 * KSTR, 64);
  asm volatile("s_waitcnt vmcnt(6)");      // drains step-0's 4 regions
  SBAR();
  SCHED(0);

  bf16x8 af[4][2], b0f[2][2], b1f[2][2];
  // pre-loop reads for step 0: B0 then A0 (12 ds_reads, drained at P0's lgkm(4))
#pragma unroll
  for (int j = 0; j < 2; ++j) {
    b0f[j][0] = *(const bf16x8*)(lds[0][2] + offB[j][0]);
    b0f[j][1] = *(const bf16x8*)(lds[0][2] + offB[j][1]);
  }
#pragma unroll
  for (int m = 0; m < 4; ++m) {
    af[m][0] = *(const bf16x8*)(lds[0][0] + offA[m][0]);
    af[m][1] = *(const bf16x8*)(lds[0][0] + offA[m][1]);
  }
  SCHED(0);

#pragma unroll 1
  for (int t = 0; t < NTK; ++t) {
    const int buf = t & 1;
    const bf16_t* LA1 = lds[buf][1];
    const bf16_t* LB1 = lds[buf][3];
    const bf16_t* NA0 = lds[buf ^ 1][0];
    const bf16_t* NB0 = lds[buf ^ 1][2];
    // ---- P0: MFMA A0 x B0 -> acc[0-3][0,1]; pre-read B1(t); stage A1(t+1)
    if (t + 1 < NTK) STG(lds[buf ^ 1][1], Ab + (size_t)128 * KSTR, (t + 1) * 64);
#pragma unroll
    for (int j = 0; j < 2; ++j) {
      b1f[j][0] = *(const bf16x8*)(LB1 + offB[j][0]);
      b1f[j][1] = *(const bf16x8*)(LB1 + offB[j][1]);
    }
    SCHED(0);
    asm volatile("s_waitcnt lgkmcnt(4)");  // A0+B0 frags done; B1 still in flight
    SBAR();
    SCHED(0);
    PRIO(1);
#pragma unroll
    for (int m = 0; m < 4; ++m)
#pragma unroll
      for (int j = 0; j < 2; ++j) {
        acc[m][j] = MFMA16(af[m][0], b0f[j][0], acc[m][j], 0, 0, 0);
        acc[m][j] = MFMA16(af[m][1], b0f[j][1], acc[m][j], 0, 0, 0);
      }
    PRIO(0);
    SCHED(0);
    // ---- P1: MFMA A0 x B1 -> acc[0-3][2,3]; stage A0(t+2); post-read A1(t) into af
    if (t + 2 < NTK) STG(lds[buf][0], Ab, (t + 2) * 64);
    SCHED(0);
    asm volatile("s_waitcnt lgkmcnt(0)");  // B1 frags done
    SBAR();
    SCHED(0);
    PRIO(1);
#pragma unroll
    for (int m = 0; m < 4; ++m)
#pragma unroll
      for (int j = 0; j < 2; ++j) {
        acc[m][2 + j] = MFMA16(af[m][0], b1f[j][0], acc[m][2 + j], 0, 0, 0);
        acc[m][2 + j] = MFMA16(af[m][1], b1f[j][1], acc[m][2 + j], 0, 0, 0);
      }
    PRIO(0);
    SCHED(0);
#pragma unroll
    for (int m = 0; m < 4; ++m) {
      af[m][0] = *(const bf16x8*)(LA1 + offA[m][0]);
      af[m][1] = *(const bf16x8*)(LA1 + offA[m][1]);
    }
    SCHED(0);
    // ---- P2: MFMA A1 x B0 -> acc[4-7][0,1]; stage B0(t+2)
    if (t + 2 < NTK) STG(lds[buf][2], Bb, (t + 2) * 64);
    SCHED(0);
    asm volatile("s_waitcnt lgkmcnt(0)");  // A1 frags done
    SBAR();
    SCHED(0);
    PRIO(1);
#pragma unroll
    for (int m = 0; m < 4; ++m)
#pragma unroll
      for (int j = 0; j < 2; ++j) {
        acc[4 + m][j] = MFMA16(af[m][0], b0f[j][0], acc[4 + m][j], 0, 0, 0);
        acc[4 + m][j] = MFMA16(af[m][1], b0f[j][1], acc[4 + m][j], 0, 0, 0);
      }
    PRIO(0);
    SCHED(0);
    // ---- P3: MFMA A1 x B1 -> acc[4-7][2,3]; stage B1(t+2); vmcnt publish; next-step reads
    if (t + 2 < NTK) STG(lds[buf][3], Bb + (size_t)128 * KSTR, (t + 2) * 64);
    SCHED(0);
    if (t < NTK - 2)       { asm volatile("s_waitcnt vmcnt(6)"); }
    else if (t == NTK - 2) { asm volatile("s_waitcnt vmcnt(0)"); }
    SBAR();
    SCHED(0);
    if (t + 1 < NTK) {     // B0(t+1) frags (published by the vmcnt+barrier above)
#pragma unroll
      for (int j = 0; j < 2; ++j) {
        b0f[j][0] = *(const bf16x8*)(NB0 + offB[j][0]);
        b0f[j][1] = *(const bf16x8*)(NB0 + offB[j][1]);
      }
    }
    SCHED(0);
    PRIO(1);
#pragma unroll
    for (int m = 0; m < 4; ++m)
#pragma unroll
      for (int j = 0; j < 2; ++j) {
        acc[4 + m][2 + j] = MFMA16(af[m][0], b1f[j][0], acc[4 + m][2 + j], 0, 0, 0);
        acc[4 + m][2 + j] = MFMA16(af[m][1], b1f[j][1], acc[4 + m][2 + j], 0, 0, 0);
      }
    PRIO(0);
    SCHED(0);
    if (t + 1 < NTK) {     // A0(t+1) frags into af (WAR-safe: after P3's MFMA in order)
#pragma unroll
      for (int m = 0; m < 4; ++m) {
        af[m][0] = *(const bf16x8*)(NA0 + offA[m][0]);
        af[m][1] = *(const bf16x8*)(NA0 + offA[m][1]);
      }
    }
    SCHED(0);
  }
#undef STG

  // epilogue
#pragma unroll
  for (int i = 0; i < 8; ++i) {
    int lr = i * 32 + wm * 16 + fq * 4;
#pragma unroll
    for (int rr = 0; rr < 4; ++rr) {
      if (lr + rr < rows) {
        if constexpr (SWIGLU) {
          // acc[i][0,1]=(g,u) H-col nt*128+wn*16+fm; acc[i][2,3]=(g,u) same +64
          bf16_t* hp = O + (size_t)(m0 + lr + rr) * IM + nt * 128 + wn * 16 + fm;
          float g0 = acc[i][0][rr], u0 = acc[i][1][rr];
          hp[0] = (bf16_t)(g0 * __builtin_amdgcn_rcpf(1.f + __expf(-g0)) * u0);
          float g1 = acc[i][2][rr], u1 = acc[i][3][rr];
          hp[64] = (bf16_t)(g1 * __builtin_amdgcn_rcpf(1.f + __expf(-g1)) * u1);
        } else {
          bf16_t* yp = O + (size_t)(m0 + lr + rr) * DM + nt * 256 + wn * 16 + fm;
          yp[0]   = (bf16_t)acc[i][0][rr];
          yp[64]  = (bf16_t)acc[i][1][rr];
          yp[128] = (bf16_t)acc[i][2][rr];
          yp[192] = (bf16_t)acc[i][3][rr];
        }
      }
    }
  }
}

// ---------------- combine: out[n] = w0 * Y[slot(n,0)] + w1 * Y[slot(n,1)]
__global__ void combine_kernel(const bf16_t* __restrict__ Y, const int* __restrict__ pair_slot,
                               const float* __restrict__ topk_w, float* __restrict__ out) {
  int n = blockIdx.x;
  int t = threadIdx.x;
  int s0 = pair_slot[n * 2 + 0], s1 = pair_slot[n * 2 + 1];
  float w0 = topk_w[n * 2 + 0], w1 = topk_w[n * 2 + 1];
  bf16x4 y0 = *(const bf16x4*)(Y + (size_t)s0 * DM + t * 4);
  bf16x4 y1 = *(const bf16x4*)(Y + (size_t)s1 * DM + t * 4);
  float4 o;
  o.x = w0 * (float)y0[0] + w1 * (float)y1[0];
  o.y = w0 * (float)y0[1] + w1 * (float)y1[1];
  o.z = w0 * (float)y0[2] + w1 * (float)y1[2];
  o.w = w0 * (float)y0[3] + w1 * (float)y1[3];
  *(float4*)(out + (size_t)n * DM + t * 4) = o;
}

// ---------------- workspace layout (bytes)
static constexpr size_t OFF_TL    = 256;                               // tile list
static constexpr size_t OFF_TLE   = OFF_TL  + (size_t)MAXT * 4;
static constexpr size_t OFF_TLR   = OFF_TLE + (size_t)MAXT * 4;
static constexpr size_t OFF_NTL   = OFF_TLR + (size_t)MAXT * 4;
static constexpr size_t OFF_TOPKI = 1536;                              // [NT][2] i32
static constexpr size_t OFF_TOPKW = OFF_TOPKI + (size_t)NT * 2 * 4;    // [NT][2] f32
static constexpr size_t OFF_STOK  = OFF_TOPKW + (size_t)NT * 2 * 4;    // [NS] i32
static constexpr size_t OFF_SW    = OFF_STOK + (size_t)NS * 4;         // [NS] f32
static constexpr size_t OFF_PSLOT = OFF_SW + (size_t)NS * 4;           // [NS] i32
static constexpr size_t OFF_XG    = OFF_PSLOT + (size_t)NS * 4;        // [SCAP][DM] bf16 (Y aliases)
static constexpr size_t OFF_H     = OFF_XG + (size_t)SCAP * DM * 2;    // [SCAP][IM] bf16
static constexpr size_t OFF_WGU   = OFF_H + (size_t)SCAP * IM * 2;     // [NE][2*IM][DM] bf16
static constexpr size_t OFF_WDT   = OFF_WGU + (size_t)NE * 2 * IM * DM * 2; // [NE][DM][IM] bf16

extern "C" void kernel_launch(void* const* d_in, const int* in_sizes, int n_in,
                              void* d_out, int out_size, void* d_ws, size_t ws_size,
                              hipStream_t stream) {
  const float* x      = (const float*)d_in[0];
  const float* w_gate = (const float*)d_in[1];
  const float* wg     = (const float*)d_in[2];
  const float* wu     = (const float*)d_in[3];
  const float* wd     = (const float*)d_in[4];
  float* out = (float*)d_out;

  char* ws = (char*)d_ws;
  int*   counts   = (int*)(ws + 0);
  int*   cursors  = (int*)(ws + 32);
  int*   offsets  = (int*)(ws + 64);
  float* prob_sum = (float*)(ws + 128);
  int*   tl_m0    = (int*)(ws + OFF_TL);
  int*   tl_e     = (int*)(ws + OFF_TLE);
  int*   tl_rows  = (int*)(ws + OFF_TLR);
  int*   n_tiles  = (int*)(ws + OFF_NTL);
  int*   topk_idx = (int*)(ws + OFF_TOPKI);
  float* topk_w   = (float*)(ws + OFF_TOPKW);
  int*   slot_tok = (int*)(ws + OFF_STOK);
  float* slot_w   = (float*)(ws + OFF_SW);
  int*   pair_slot= (int*)(ws + OFF_PSLOT);
  bf16_t* Xg  = (bf16_t*)(ws + OFF_XG);
  bf16_t* Yb  = Xg;                          // Y aliases Xg (dead after gemm1; same size)
  bf16_t* Hb  = (bf16_t*)(ws + OFF_H);
  bf16_t* Wgu = (bf16_t*)(ws + OFF_WGU);
  bf16_t* Wdt = (bf16_t*)(ws + OFF_WDT);

  hipMemsetAsync(ws, 0, 256, stream);

  // weight convert: wg+wu -> packed Wgu [2*IM][DM]; wd -> Wdt [DM][IM]
  pack_gu<<<dim3(IM / 32, DM / 32, NE * 2), dim3(32, 8), 0, stream>>>(wg, wu, Wgu);
  transpose_cvt<<<dim3(DM / 32, IM / 32, NE), dim3(32, 8), 0, stream>>>(wd, Wdt, IM, DM);

  router_kernel<<<NT / 32, 256, 0, stream>>>(x, w_gate, counts, prob_sum, topk_idx, topk_w);
  scan_aux<<<1, 64, 0, stream>>>(counts, prob_sum, offsets, cursors, out + (out_size - 1),
                                 tl_m0, tl_e, tl_rows, n_tiles);
  gather_kernel<<<NS / 4, 256, 0, stream>>>(x, topk_idx, topk_w, cursors, slot_tok, slot_w,
                                            pair_slot, Xg);

  // gemm1: H = swiglu(Xg @ Wgu'); 32 x up-to-72 tiles; dead tiles exit on n_tiles
  moe_gemm<DM / 64, DM, 2 * IM, true><<<dim3(32, MAXT), 512, 0, stream>>>(
      Xg, Wgu, Hb, tl_m0, tl_e, tl_rows, n_tiles);
  // gemm2: Y = H @ Wdt'
  moe_gemm<IM / 64, IM, DM, false><<<dim3(4, MAXT), 512, 0, stream>>>(
      Hb, Wdt, Yb, tl_m0, tl_e, tl_rows, n_tiles);

  combine_kernel<<<NT, 256, 0, stream>>>(Yb, pair_slot, topk_w, out);
}

// Round 6
// 1167.020 us; speedup vs baseline: 1.0635x; 1.0140x over previous
//
#include <hip/hip_runtime.h>
#include <hip/hip_bf16.h>
#include <cstdint>
#include <cstddef>

#define NE 8          // experts
#define TK 2          // top-k
#define DM 1024       // hidden
#define IM 4096       // intermediate
#define NT 8192       // tokens (4*2048)
#define NS (NT*TK)    // total slots = 16384 (exact)
#define SCAP (NS+256) // padded rows for 256-row tile overhang
#define MAXT 72       // max 256-row tiles: sum ceil(ne/256) <= 64 + 7 = 71

typedef __bf16 bf16_t;
typedef __bf16 bf16x8 __attribute__((ext_vector_type(8)));
typedef __bf16 bf16x4 __attribute__((ext_vector_type(4)));
typedef float f32x4 __attribute__((ext_vector_type(4)));

// async global->LDS, 16B per lane. LDS side must be wave-uniform base + lane*16.
__device__ __forceinline__ void async_cp16(const bf16_t* g, bf16_t* l) {
  __builtin_amdgcn_global_load_lds(
      (__attribute__((address_space(1))) void*)(const_cast<bf16_t*>(g)),
      (__attribute__((address_space(3))) void*)(l), 16, 0, 0);
}

// ---------------- transpose + fp32->bf16 convert: src [z][R][C] f32 -> dst [z][C][R] bf16
__global__ void transpose_cvt(const float* __restrict__ src, bf16_t* __restrict__ dst,
                              int R, int C) {
  __shared__ float t[32][33];
  int bx = blockIdx.x * 32, by = blockIdx.y * 32;
  size_t zb = (size_t)blockIdx.z * R * C;
  int tx = threadIdx.x, ty = threadIdx.y;   // 32 x 8
#pragma unroll
  for (int i = 0; i < 4; ++i)
    t[ty + i*8][tx] = src[zb + (size_t)(by + ty + i*8) * C + bx + tx];
  __syncthreads();
#pragma unroll
  for (int i = 0; i < 4; ++i)
    dst[zb + (size_t)(bx + ty + i*8) * R + by + tx] = (bf16_t)t[tx][ty + i*8];
}

// ---------------- pack wg+wu -> Wgu[e][2*IM][DM] bf16, interleaved 64-col groups:
// packed row p: block=p>>7, sel=(p>>6)&1, r=p&63 -> source col block*64+r of (sel?wu:wg)
__global__ void pack_gu(const float* __restrict__ wg, const float* __restrict__ wu,
                        bf16_t* __restrict__ Wgu) {
  __shared__ float t[32][33];
  int sel = blockIdx.z & 1, e = blockIdx.z >> 1;
  const float* src = sel ? wu : wg;
  size_t zb = (size_t)e * DM * IM;
  int bx = blockIdx.x * 32, by = blockIdx.y * 32;   // bx: i-cols, by: d-rows
  int tx = threadIdx.x, ty = threadIdx.y;           // 32 x 8
#pragma unroll
  for (int i = 0; i < 4; ++i)
    t[ty + i*8][tx] = src[zb + (size_t)(by + ty + i*8) * IM + bx + tx];
  __syncthreads();
#pragma unroll
  for (int i = 0; i < 4; ++i) {
    int icol = bx + ty + i*8;
    int p = ((icol >> 6) << 7) + (sel << 6) + (icol & 63);
    Wgu[((size_t)e * (2*IM) + p) * DM + by + tx] = (bf16_t)t[tx][ty + i*8];
  }
}

// ---------------- router: logits, softmax, top-2, renorm; per-expert counts + prob sums
__global__ void router_kernel(const float* __restrict__ x, const float* __restrict__ wgate,
                              int* __restrict__ counts, float* __restrict__ prob_sum,
                              int* __restrict__ topk_idx, float* __restrict__ topk_w) {
  __shared__ float s_psum[NE];
  __shared__ int s_cnt[NE];
  int tid = threadIdx.x;
  if (tid < NE) { s_psum[tid] = 0.f; s_cnt[tid] = 0; }
  __syncthreads();
  int lane = tid & 63, wv = tid >> 6;
  for (int t = 0; t < 8; ++t) {             // 4 waves x 8 tokens = 32 tokens/block
    int n = blockIdx.x * 32 + wv * 8 + t;
    float acc[NE];
#pragma unroll
    for (int e = 0; e < NE; ++e) acc[e] = 0.f;
#pragma unroll
    for (int j = 0; j < 16; ++j) {
      int d = j * 64 + lane;
      float xv = x[(size_t)n * DM + d];
#pragma unroll
      for (int e = 0; e < NE; ++e) acc[e] += xv * wgate[e * DM + d];
    }
#pragma unroll
    for (int e = 0; e < NE; ++e) {
#pragma unroll
      for (int off = 32; off > 0; off >>= 1) acc[e] += __shfl_xor(acc[e], off);
    }
    if (lane == 0) {
      float mx = acc[0];
#pragma unroll
      for (int e = 1; e < NE; ++e) mx = fmaxf(mx, acc[e]);
      float p[NE], s = 0.f;
#pragma unroll
      for (int e = 0; e < NE; ++e) { p[e] = __expf(acc[e] - mx); s += p[e]; }
      float inv = 1.f / s;
#pragma unroll
      for (int e = 0; e < NE; ++e) p[e] *= inv;
      int i0 = 0;
      for (int e = 1; e < NE; ++e) if (p[e] > p[i0]) i0 = e;     // ties -> lower idx (matches top_k)
      int i1 = (i0 == 0) ? 1 : 0;
      for (int e = 0; e < NE; ++e) if (e != i0 && p[e] > p[i1]) i1 = e;
      float rs = 1.f / (p[i0] + p[i1]);
      topk_idx[n * 2 + 0] = i0; topk_idx[n * 2 + 1] = i1;
      topk_w[n * 2 + 0] = p[i0] * rs; topk_w[n * 2 + 1] = p[i1] * rs;
      atomicAdd(&s_cnt[i0], 1); atomicAdd(&s_cnt[i1], 1);
#pragma unroll
      for (int e = 0; e < NE; ++e) atomicAdd(&s_psum[e], p[e]);
    }
  }
  __syncthreads();
  if (tid < NE) { atomicAdd(&counts[tid], s_cnt[tid]); atomicAdd(&prob_sum[tid], s_psum[tid]); }
}

// ---------------- scan counts, cursors, aux loss, and build the 256-row tile list
__global__ void scan_aux(const int* __restrict__ counts, const float* __restrict__ prob_sum,
                         int* __restrict__ offsets, int* __restrict__ cursors,
                         float* __restrict__ aux_out, int* __restrict__ tl_m0,
                         int* __restrict__ tl_e, int* __restrict__ tl_rows,
                         int* __restrict__ n_tiles) {
  if (threadIdx.x == 0) {
    int off = 0;
    float aux = 0.f;
    int t = 0;
    for (int e = 0; e < NE; ++e) {
      offsets[e] = off; cursors[e] = off;
      int c = counts[e];
      float f = (float)c * (1.f / (float)NS);
      float p = prob_sum[e] * (1.f / (float)NT);
      aux += f * p;
      for (int m = 0; m * 256 < c && t < MAXT; ++m, ++t) {
        tl_m0[t] = off + m * 256;
        tl_e[t] = e;
        tl_rows[t] = min(256, c - m * 256);
      }
      off += c;
    }
    offsets[NE] = off;
    *n_tiles = t;
    *aux_out = 0.02f * 8.f * aux;
  }
}

// ---------------- gather tokens into per-expert compact bf16 rows (vectorized f32x4->bf16x4)
__global__ void gather_kernel(const float* __restrict__ x, const int* __restrict__ topk_idx,
                              const float* __restrict__ topk_w, int* __restrict__ cursors,
                              int* __restrict__ slot_token, float* __restrict__ slot_w,
                              int* __restrict__ pair_slot, bf16_t* __restrict__ Xg) {
  int lane = threadIdx.x & 63, wv = threadIdx.x >> 6;
  int pair = blockIdx.x * 4 + wv;           // (token, k)
  int n = pair >> 1, k = pair & 1;
  int e = topk_idx[n * 2 + k];
  int slot = 0;
  if (lane == 0) slot = atomicAdd(&cursors[e], 1);
  slot = __shfl(slot, 0);
  if (lane == 0) {
    slot_token[slot] = n; slot_w[slot] = topk_w[n * 2 + k];
    pair_slot[pair] = slot;
  }
#pragma unroll
  for (int j = 0; j < 4; ++j) {
    int d4 = j * 256 + lane * 4;
    float4 v = *(const float4*)(x + (size_t)n * DM + d4);
    bf16x4 o;
    o[0] = (bf16_t)v.x; o[1] = (bf16_t)v.y; o[2] = (bf16_t)v.z; o[3] = (bf16_t)v.w;
    *(bf16x4*)(Xg + (size_t)slot * DM + d4) = o;
  }
}

// ============ unified 256-tile MoE GEMM, software-pipelined 4-phase schedule ============
// Per block: 256 A-rows (tile list) x 256 B-rows (nt) over K-chunk kh (split-K).
// 8 waves 2Mx4N, per-wave 128x64. LDS: 2 bufs x 4 regions (A0,A1,B0,B1) x 128x64 bf16 =
// 128 KiB, XOR-swizzled chunks. One barrier per phase. Wait order per phase:
//   P0: lgkm(4) BEFORE barrier (drains ancient A0/B0 reads; makes the P1 A0-overwrite
//       barrier-proven -- the reads it waits on were issued a full MFMA window ago, so
//       no latency-hiding is lost);
//   P1/P2: barrier THEN lgkm(0) (fresh A1/B1 reads hide under barrier-arrival skew;
//       airtight: each region's readers pass an lgkm(0) before the barrier preceding
//       its overwrite, verified per-region).
// Frag-reads for phase k issue in phase k-1's MFMA window. Staging via 8 persistent
// per-thread pointers bumped +64 elems/iter (kills 64-bit address recompute VALU).
// vmcnt(6) at P3 publishes exactly step t+1's 4 regions; drained to 0 at t==NTK-2.
#define MFMA16 __builtin_amdgcn_mfma_f32_16x16x32_bf16
#define SBAR  __builtin_amdgcn_s_barrier
#define SCHED __builtin_amdgcn_sched_barrier
#define PRIO  __builtin_amdgcn_s_setprio

template<int NTK, int KSTR, int BROWS, bool SWIGLU, int KSPLIT>
__global__ __launch_bounds__(512, 2) void moe_gemm(
    const bf16_t* __restrict__ A, const bf16_t* __restrict__ Bw,
    void* __restrict__ O,
    const int* __restrict__ tl_m0, const int* __restrict__ tl_e,
    const int* __restrict__ tl_rows, const int* __restrict__ n_tiles) {
  int ty = blockIdx.y;
  if (ty >= *n_tiles) return;
  int m0 = tl_m0[ty];
  int e  = tl_e[ty];
  int rows = tl_rows[ty];
  int nt = blockIdx.x;
  int kh = (KSPLIT > 1) ? (int)blockIdx.z : 0;
  constexpr int KC = NTK * 64;              // K-chunk this block covers

  __shared__ bf16_t lds[2][4][128 * 64];   // [buf][region: 0=A0,1=A1,2=B0,3=B1]

  int tid = threadIdx.x, lane = tid & 63, wv = tid >> 6;
  int fm = lane & 15, fq = lane >> 4;
  int wm = wv >> 2, wn = wv & 3;

  const bf16_t* Ab = A + (size_t)m0 * KSTR + kh * KC;
  const bf16_t* Bb = Bw + ((size_t)e * BROWS + (size_t)nt * 256) * KSTR + kh * KC;

  // staging: thread covers chunk tid (row sr) and row sr+64 (same swizzle phase)
  int sr = tid >> 3;
  int sgc = ((tid & 7) ^ (sr & 7)) << 3;   // inverse-swizzled source col (elems)
  int sldo = tid * 8;                      // linear LDS elem offset; +4096 for 2nd half

#define STG(LDST, GBASE, COL) do {                                         \
    const bf16_t* _g = (GBASE);                                            \
    async_cp16(_g + (size_t)sr * KSTR + (COL) + sgc, (LDST) + sldo);       \
    async_cp16(_g + (size_t)(sr + 64) * KSTR + (COL) + sgc, (LDST) + sldo + 4096); \
  } while (0)
#define STG2(LDST, PLO, PHI) do {                                          \
    async_cp16((PLO), (LDST) + sldo);                                      \
    async_cp16((PHI), (LDST) + sldo + 4096);                               \
  } while (0)

  // ds_read elem offsets within a 128x64 region (XOR swizzle re-applied)
  int offA[4][2], offB[2][2];
#pragma unroll
  for (int m = 0; m < 4; ++m) {
    int r = m * 32 + wm * 16 + fm;
#pragma unroll
    for (int ks = 0; ks < 2; ++ks)
      offA[m][ks] = r * 64 + (((ks * 4 + fq) ^ (r & 7)) << 3);
  }
#pragma unroll
  for (int jh = 0; jh < 2; ++jh) {
    int r = jh * 64 + wn * 16 + fm;
#pragma unroll
    for (int ks = 0; ks < 2; ++ks)
      offB[jh][ks] = r * 64 + (((ks * 4 + fq) ^ (r & 7)) << 3);
  }

  f32x4 acc[8][4];
#pragma unroll
  for (int i = 0; i < 8; ++i)
#pragma unroll
    for (int j = 0; j < 4; ++j) acc[i][j] = (f32x4){0.f, 0.f, 0.f, 0.f};

  // prologue: stage halves (0,A0)(0,B0)(0,B1)(0,A1)(1,A0)(1,B0)(1,B1)
  STG(lds[0][0], Ab, 0);
  STG(lds[0][2], Bb, 0);
  STG(lds[0][3], Bb + (size_t)128 * KSTR, 0);
  STG(lds[0][1], Ab + (size_t)128 * KSTR, 0);
  STG(lds[1][0], Ab, 64);
  STG(lds[1][2], Bb, 64);
  STG(lds[1][3], Bb + (size_t)128 * KSTR, 64);

  // persistent staging pointers at their first in-loop columns (A1: col 64; rest: col 128)
  const bf16_t* qA1a = Ab + (size_t)(128 + sr) * KSTR + sgc + 64;
  const bf16_t* qA1b = Ab + (size_t)(192 + sr) * KSTR + sgc + 64;
  const bf16_t* qA0a = Ab + (size_t)sr * KSTR + sgc + 128;
  const bf16_t* qA0b = Ab + (size_t)(64 + sr) * KSTR + sgc + 128;
  const bf16_t* qB0a = Bb + (size_t)sr * KSTR + sgc + 128;
  const bf16_t* qB0b = Bb + (size_t)(64 + sr) * KSTR + sgc + 128;
  const bf16_t* qB1a = Bb + (size_t)(128 + sr) * KSTR + sgc + 128;
  const bf16_t* qB1b = Bb + (size_t)(192 + sr) * KSTR + sgc + 128;

  asm volatile("s_waitcnt vmcnt(6)");      // drains step-0's 4 regions
  SBAR();
  SCHED(0);

  bf16x8 af[4][2], b0f[2][2], b1f[2][2];
  // pre-loop reads for step 0: B0 then A0 (12 ds_reads, drained at P0's lgkm(4))
#pragma unroll
  for (int j = 0; j < 2; ++j) {
    b0f[j][0] = *(const bf16x8*)(lds[0][2] + offB[j][0]);
    b0f[j][1] = *(const bf16x8*)(lds[0][2] + offB[j][1]);
  }
#pragma unroll
  for (int m = 0; m < 4; ++m) {
    af[m][0] = *(const bf16x8*)(lds[0][0] + offA[m][0]);
    af[m][1] = *(const bf16x8*)(lds[0][0] + offA[m][1]);
  }
  SCHED(0);

#pragma unroll 1
  for (int t = 0; t < NTK; ++t) {
    const int buf = t & 1;
    const bf16_t* LA1 = lds[buf][1];
    const bf16_t* LB1 = lds[buf][3];
    const bf16_t* NA0 = lds[buf ^ 1][0];
    const bf16_t* NB0 = lds[buf ^ 1][2];
    // ---- P0: MFMA A0 x B0 -> acc[0-3][0,1]; pre-read B1(t); stage A1(t+1)
    if (t + 1 < NTK) STG2(lds[buf ^ 1][1], qA1a, qA1b);
#pragma unroll
    for (int j = 0; j < 2; ++j) {
      b1f[j][0] = *(const bf16x8*)(LB1 + offB[j][0]);
      b1f[j][1] = *(const bf16x8*)(LB1 + offB[j][1]);
    }
    SCHED(0);
    asm volatile("s_waitcnt lgkmcnt(4)");  // A0+B0 frags done (ancient); B1 in flight
    SBAR();                                 // -> P1's A0-overwrite is barrier-proven
    SCHED(0);
    PRIO(1);
#pragma unroll
    for (int m = 0; m < 4; ++m)
#pragma unroll
      for (int j = 0; j < 2; ++j) {
        acc[m][j] = MFMA16(af[m][0], b0f[j][0], acc[m][j], 0, 0, 0);
        acc[m][j] = MFMA16(af[m][1], b0f[j][1], acc[m][j], 0, 0, 0);
      }
    PRIO(0);
    SCHED(0);
    // ---- P1: MFMA A0 x B1 -> acc[0-3][2,3]; stage A0(t+2); post-read A1(t) into af
    if (t + 2 < NTK) STG2(lds[buf][0], qA0a, qA0b);
    SCHED(0);
    SBAR();
    asm volatile("s_waitcnt lgkmcnt(0)");  // B1 frags done (hides under barrier skew)
    SCHED(0);
    PRIO(1);
#pragma unroll
    for (int m = 0; m < 4; ++m)
#pragma unroll
      for (int j = 0; j < 2; ++j) {
        acc[m][2 + j] = MFMA16(af[m][0], b1f[j][0], acc[m][2 + j], 0, 0, 0);
        acc[m][2 + j] = MFMA16(af[m][1], b1f[j][1], acc[m][2 + j], 0, 0, 0);
      }
    PRIO(0);
    SCHED(0);
#pragma unroll
    for (int m = 0; m < 4; ++m) {
      af[m][0] = *(const bf16x8*)(LA1 + offA[m][0]);
      af[m][1] = *(const bf16x8*)(LA1 + offA[m][1]);
    }
    SCHED(0);
    // ---- P2: MFMA A1 x B0 -> acc[4-7][0,1]; stage B0(t+2)
    if (t + 2 < NTK) STG2(lds[buf][2], qB0a, qB0b);
    SCHED(0);
    SBAR();
    asm volatile("s_waitcnt lgkmcnt(0)");  // A1 frags done (fresh; hides under skew)
    SCHED(0);
    PRIO(1);
#pragma unroll
    for (int m = 0; m < 4; ++m)
#pragma unroll
      for (int j = 0; j < 2; ++j) {
        acc[4 + m][j] = MFMA16(af[m][0], b0f[j][0], acc[4 + m][j], 0, 0, 0);
        acc[4 + m][j] = MFMA16(af[m][1], b0f[j][1], acc[4 + m][j], 0, 0, 0);
      }
    PRIO(0);
    SCHED(0);
    // ---- P3: MFMA A1 x B1 -> acc[4-7][2,3]; stage B1(t+2); vmcnt publish; next-step reads
    if (t + 2 < NTK) STG2(lds[buf][3], qB1a, qB1b);
    SCHED(0);
    if (t < NTK - 2)       { asm volatile("s_waitcnt vmcnt(6)"); }
    else if (t == NTK - 2) { asm volatile("s_waitcnt vmcnt(0)"); }
    SBAR();
    SCHED(0);
    if (t + 1 < NTK) {     // B0(t+1) frags (published by the vmcnt+barrier above)
#pragma unroll
      for (int j = 0; j < 2; ++j) {
        b0f[j][0] = *(const bf16x8*)(NB0 + offB[j][0]);
        b0f[j][1] = *(const bf16x8*)(NB0 + offB[j][1]);
      }
    }
    SCHED(0);
    PRIO(1);
#pragma unroll
    for (int m = 0; m < 4; ++m)
#pragma unroll
      for (int j = 0; j < 2; ++j) {
        acc[4 + m][2 + j] = MFMA16(af[m][0], b1f[j][0], acc[4 + m][2 + j], 0, 0, 0);
        acc[4 + m][2 + j] = MFMA16(af[m][1], b1f[j][1], acc[4 + m][2 + j], 0, 0, 0);
      }
    PRIO(0);
    SCHED(0);
    if (t + 1 < NTK) {     // A0(t+1) frags into af (WAR-safe: after P3's MFMA in order)
#pragma unroll
      for (int m = 0; m < 4; ++m) {
        af[m][0] = *(const bf16x8*)(NA0 + offA[m][0]);
        af[m][1] = *(const bf16x8*)(NA0 + offA[m][1]);
      }
    }
    SCHED(0);
    // bump staging pointers (uniform, 8 x 64 elems)
    qA1a += 64; qA1b += 64; qA0a += 64; qA0b += 64;
    qB0a += 64; qB0b += 64; qB1a += 64; qB1b += 64;
  }
#undef STG
#undef STG2

  // epilogue
#pragma unroll
  for (int i = 0; i < 8; ++i) {
    int lr = i * 32 + wm * 16 + fq * 4;
#pragma unroll
    for (int rr = 0; rr < 4; ++rr) {
      if (lr + rr < rows) {
        if constexpr (SWIGLU) {
          // acc[i][0,1]=(g,u) H-col nt*128+wn*16+fm; acc[i][2,3]=(g,u) same +64
          bf16_t* hp = (bf16_t*)O + (size_t)(m0 + lr + rr) * IM + nt * 128 + wn * 16 + fm;
          float g0 = acc[i][0][rr], u0 = acc[i][1][rr];
          hp[0] = (bf16_t)(g0 * __builtin_amdgcn_rcpf(1.f + __expf(-g0)) * u0);
          float g1 = acc[i][2][rr], u1 = acc[i][3][rr];
          hp[64] = (bf16_t)(g1 * __builtin_amdgcn_rcpf(1.f + __expf(-g1)) * u1);
        } else {
          // f32 partial for K-half kh
          float* yp = (float*)O + (size_t)kh * ((size_t)NS * DM)
                      + (size_t)(m0 + lr + rr) * DM + nt * 256 + wn * 16 + fm;
          yp[0]   = acc[i][0][rr];
          yp[64]  = acc[i][1][rr];
          yp[128] = acc[i][2][rr];
          yp[192] = acc[i][3][rr];
        }
      }
    }
  }
}

// ---------------- combine: out[n] = w0*(Y0+Y1)[slot(n,0)] + w1*(Y0+Y1)[slot(n,1)]
__global__ void combine_kernel(const float* __restrict__ Yp, const int* __restrict__ pair_slot,
                               const float* __restrict__ topk_w, float* __restrict__ out) {
  int n = blockIdx.x;
  int t = threadIdx.x;
  int s0 = pair_slot[n * 2 + 0], s1 = pair_slot[n * 2 + 1];
  float w0 = topk_w[n * 2 + 0], w1 = topk_w[n * 2 + 1];
  const size_t half = (size_t)NS * DM;
  float4 a0 = *(const float4*)(Yp + (size_t)s0 * DM + t * 4);
  float4 a1 = *(const float4*)(Yp + half + (size_t)s0 * DM + t * 4);
  float4 b0 = *(const float4*)(Yp + (size_t)s1 * DM + t * 4);
  float4 b1 = *(const float4*)(Yp + half + (size_t)s1 * DM + t * 4);
  float4 o;
  o.x = w0 * (a0.x + a1.x) + w1 * (b0.x + b1.x);
  o.y = w0 * (a0.y + a1.y) + w1 * (b0.y + b1.y);
  o.z = w0 * (a0.z + a1.z) + w1 * (b0.z + b1.z);
  o.w = w0 * (a0.w + a1.w) + w1 * (b0.w + b1.w);
  *(float4*)(out + (size_t)n * DM + t * 4) = o;
}

// ---------------- workspace layout (bytes)
static constexpr size_t OFF_TL    = 256;                               // tile list
static constexpr size_t OFF_TLE   = OFF_TL  + (size_t)MAXT * 4;
static constexpr size_t OFF_TLR   = OFF_TLE + (size_t)MAXT * 4;
static constexpr size_t OFF_NTL   = OFF_TLR + (size_t)MAXT * 4;
static constexpr size_t OFF_TOPKI = 1536;                              // [NT][2] i32
static constexpr size_t OFF_TOPKW = OFF_TOPKI + (size_t)NT * 2 * 4;    // [NT][2] f32
static constexpr size_t OFF_STOK  = OFF_TOPKW + (size_t)NT * 2 * 4;    // [NS] i32
static constexpr size_t OFF_SW    = OFF_STOK + (size_t)NS * 4;         // [NS] f32
static constexpr size_t OFF_PSLOT = OFF_SW + (size_t)NS * 4;           // [NS] i32
static constexpr size_t OFF_XG    = OFF_PSLOT + (size_t)NS * 4;        // [SCAP][DM] bf16
static constexpr size_t OFF_H     = OFF_XG + (size_t)SCAP * DM * 2;    // [SCAP][IM] bf16
static constexpr size_t OFF_WGU   = OFF_H + (size_t)SCAP * IM * 2;     // [NE][2*IM][DM] bf16
static constexpr size_t OFF_WDT   = OFF_WGU + (size_t)NE * 2 * IM * DM * 2; // [NE][DM][IM] bf16
// Y f32 partials [2][NS][DM] alias the Wgu region (dead after gemm1): 2*64MB == 128MB == |Wgu|

extern "C" void kernel_launch(void* const* d_in, const int* in_sizes, int n_in,
                              void* d_out, int out_size, void* d_ws, size_t ws_size,
                              hipStream_t stream) {
  const float* x      = (const float*)d_in[0];
  const float* w_gate = (const float*)d_in[1];
  const float* wg     = (const float*)d_in[2];
  const float* wu     = (const float*)d_in[3];
  const float* wd     = (const float*)d_in[4];
  float* out = (float*)d_out;

  char* ws = (char*)d_ws;
  int*   counts   = (int*)(ws + 0);
  int*   cursors  = (int*)(ws + 32);
  int*   offsets  = (int*)(ws + 64);
  float* prob_sum = (float*)(ws + 128);
  int*   tl_m0    = (int*)(ws + OFF_TL);
  int*   tl_e     = (int*)(ws + OFF_TLE);
  int*   tl_rows  = (int*)(ws + OFF_TLR);
  int*   n_tiles  = (int*)(ws + OFF_NTL);
  int*   topk_idx = (int*)(ws + OFF_TOPKI);
  float* topk_w   = (float*)(ws + OFF_TOPKW);
  int*   slot_tok = (int*)(ws + OFF_STOK);
  float* slot_w   = (float*)(ws + OFF_SW);
  int*   pair_slot= (int*)(ws + OFF_PSLOT);
  bf16_t* Xg  = (bf16_t*)(ws + OFF_XG);
  bf16_t* Hb  = (bf16_t*)(ws + OFF_H);
  bf16_t* Wgu = (bf16_t*)(ws + OFF_WGU);
  bf16_t* Wdt = (bf16_t*)(ws + OFF_WDT);
  float*  Yp  = (float*)(ws + OFF_WGU);      // aliases Wgu (dead after gemm1)

  hipMemsetAsync(ws, 0, 256, stream);

  // weight convert: wg+wu -> packed Wgu [2*IM][DM]; wd -> Wdt [DM][IM]
  pack_gu<<<dim3(IM / 32, DM / 32, NE * 2), dim3(32, 8), 0, stream>>>(wg, wu, Wgu);
  transpose_cvt<<<dim3(DM / 32, IM / 32, NE), dim3(32, 8), 0, stream>>>(wd, Wdt, IM, DM);

  router_kernel<<<NT / 32, 256, 0, stream>>>(x, w_gate, counts, prob_sum, topk_idx, topk_w);
  scan_aux<<<1, 64, 0, stream>>>(counts, prob_sum, offsets, cursors, out + (out_size - 1),
                                 tl_m0, tl_e, tl_rows, n_tiles);
  gather_kernel<<<NS / 4, 256, 0, stream>>>(x, topk_idx, topk_w, cursors, slot_tok, slot_w,
                                            pair_slot, Xg);

  // gemm1: H = swiglu(Xg @ Wgu'); 32 nt x up-to-72 tiles
  moe_gemm<DM / 64, DM, 2 * IM, true, 1><<<dim3(32, MAXT, 1), 512, 0, stream>>>(
      Xg, Wgu, (void*)Hb, tl_m0, tl_e, tl_rows, n_tiles);
  // gemm2: Yp[kh] = H @ Wdt' (split-K=2, f32 partials into dead Wgu region)
  moe_gemm<IM / 128, IM, DM, false, 2><<<dim3(4, MAXT, 2), 512, 0, stream>>>(
      Hb, Wdt, (void*)Yp, tl_m0, tl_e, tl_rows, n_tiles);

  combine_kernel<<<NT, 256, 0, stream>>>(Yp, pair_slot, topk_w, out);
}